// Round 1
// baseline (51.260 us; speedup 1.0000x reference)
//
#include <hip/hip_runtime.h>

#define MARGIN 1.0f
#define LAMDA  0.003f
#define EPS_H  1e-9f

// constant term: LAMDA * 4 levels * (B*N=2048) * log(2*pi)
#define E2_CONST (0.003f * 4.0f * 2048.0f * 1.8378770664093453f)

__global__ __launch_bounds__(256) void gn_task_kernel(
    const float* __restrict__ fa0, const float* __restrict__ fa1,
    const float* __restrict__ fa2, const float* __restrict__ fa3,
    const float* __restrict__ fb0, const float* __restrict__ fb1,
    const float* __restrict__ fb2, const float* __restrict__ fb3,
    const int* __restrict__ ka, const int* __restrict__ kb,
    const int* __restrict__ na, const int* __restrict__ nb,
    float* __restrict__ partial)
{
    const int wave = threadIdx.x >> 6;
    const int lane = threadIdx.x & 63;          // lane == channel c (C = 64)
    const int task = blockIdx.x * 4 + wave;     // 8192 tasks total
    const int level = task >> 11;               // 2048 tasks per level
    const int n     = task & 2047;              // point id in [0, B*N)
    const int b     = n >> 9;                   // N = 512
    const int j     = n & 511;
    const int shift = 3 - level;
    const int S     = 32 << level;

    const float* fa; const float* fb;
    switch (level) {
        case 0:  fa = fa0; fb = fb0; break;
        case 1:  fa = fa1; fb = fb1; break;
        case 2:  fa = fa2; fb = fb2; break;
        default: fa = fa3; fb = fb3; break;
    }

    const int pidx = (b * 512 + j) * 2;
    // idx[...,0] = x (W index), idx[...,1] = y (H index); access f[b, c, y, x]
    const int kax = ka[pidx]     >> shift;
    const int kay = ka[pidx + 1] >> shift;
    const int kbx = kb[pidx]     >> shift;
    const int kby = kb[pidx + 1] >> shift;
    const int nax = na[pidx]     >> shift;
    const int nay = na[pidx + 1] >> shift;
    const int nbx = nb[pidx]     >> shift;
    const int nby = nb[pidx + 1] >> shift;

    const int plane = (b * 64 + lane) * (S * S);

    const float va  = fa[plane + kay * S + kax];   // fa_pos
    const float vb  = fb[plane + kby * S + kbx];   // fb_pos (= f_s)
    const float vna = fa[plane + nay * S + nax];   // fa_neg
    const float vnb = fb[plane + nby * S + nbx];   // fb_neg

    // On-the-fly central differences of fb at (kby, kbx) — matches grad_axis:
    // boundary: one-sided diff (scale 1); interior: 0.5*(f[i+1]-f[i-1]).
    const int   xm = (kbx > 0)     ? kbx - 1 : 0;
    const int   xp = (kbx < S - 1) ? kbx + 1 : S - 1;
    const float sx = (kbx > 0 && kbx < S - 1) ? 0.5f : 1.0f;
    const float Jx = (fb[plane + kby * S + xp] - fb[plane + kby * S + xm]) * sx;

    const int   ym = (kby > 0)     ? kby - 1 : 0;
    const int   yp = (kby < S - 1) ? kby + 1 : S - 1;
    const float sy = (kby > 0 && kby < S - 1) ? 0.5f : 1.0f;
    const float Jy = (fb[plane + yp * S + kbx] - fb[plane + ym * S + kbx]) * sy;

    // per-lane partials
    const float dpos = va - vb;
    const float dneg = vna - vnb;
    const float mneg = fmaxf(MARGIN - dneg, 0.0f);
    const float r    = vb - va;                    // f_s - f_t

    float vals[7];
    vals[0] = dpos * dpos;      // s_pos
    vals[1] = mneg * mneg;      // s_neg
    vals[2] = Jx * Jx;          // Hxx
    vals[3] = Jx * Jy;          // Hxy
    vals[4] = Jy * Jy;          // Hyy
    vals[5] = Jx * r;           // bx
    vals[6] = Jy * r;           // by

    // wave-wide (64-lane) butterfly reduction
    #pragma unroll
    for (int mask = 32; mask >= 1; mask >>= 1) {
        #pragma unroll
        for (int t = 0; t < 7; ++t)
            vals[t] += __shfl_xor(vals[t], mask, 64);
    }

    if (lane == 0) {
        const float Hxx = vals[2] + EPS_H;
        const float Hxy = vals[3];
        const float Hyy = vals[4] + EPS_H;
        const float bX  = vals[5];
        const float bY  = vals[6];
        const float det = Hxx * Hyy - Hxy * Hxy;
        // e1_n = 0.5 * b^T H^{-1} b  (since d = H^{-1} b exactly: ub == xs)
        const float e1  = 0.5f * (Hyy * bX * bX - 2.0f * Hxy * bX * bY + Hxx * bY * bY) / det;
        const float out = (vals[0] + vals[1]) * (1.0f / 512.0f)
                        + LAMDA * (e1 - 0.5f * logf(det));
        partial[task] = out;
    }
}

__global__ __launch_bounds__(256) void gn_reduce_kernel(
    const float* __restrict__ partial, float* __restrict__ out)
{
    __shared__ float sm[256];
    float s = 0.0f;
    // fixed-order strided sum -> deterministic across replays
    for (int i = threadIdx.x; i < 8192; i += 256)
        s += partial[i];
    sm[threadIdx.x] = s;
    __syncthreads();
    #pragma unroll
    for (int off = 128; off >= 1; off >>= 1) {
        if (threadIdx.x < off)
            sm[threadIdx.x] += sm[threadIdx.x + off];
        __syncthreads();
    }
    if (threadIdx.x == 0)
        out[0] = sm[0] + E2_CONST;
}

extern "C" void kernel_launch(void* const* d_in, const int* in_sizes, int n_in,
                              void* d_out, int out_size, void* d_ws, size_t ws_size,
                              hipStream_t stream) {
    const float* fa0 = (const float*)d_in[0];
    const float* fa1 = (const float*)d_in[1];
    const float* fa2 = (const float*)d_in[2];
    const float* fa3 = (const float*)d_in[3];
    const float* fb0 = (const float*)d_in[4];
    const float* fb1 = (const float*)d_in[5];
    const float* fb2 = (const float*)d_in[6];
    const float* fb3 = (const float*)d_in[7];
    const int*   ka  = (const int*)d_in[8];
    const int*   kb  = (const int*)d_in[9];
    const int*   na  = (const int*)d_in[10];
    const int*   nb  = (const int*)d_in[11];

    float* partial = (float*)d_ws;      // 8192 floats = 32 KiB
    float* out     = (float*)d_out;

    gn_task_kernel<<<2048, 256, 0, stream>>>(fa0, fa1, fa2, fa3,
                                             fb0, fb1, fb2, fb3,
                                             ka, kb, na, nb, partial);
    gn_reduce_kernel<<<1, 256, 0, stream>>>(partial, out);
}